// Round 1
// baseline (96.642 us; speedup 1.0000x reference)
//
#include <hip/hip_runtime.h>

// ChannelSymmetry: Y[b,c,t] = X[b, sc, t]
//   sc = (c < 32 && swap_mask[b][c>>1]) ? c^1 : c
// B=128, C=64, T=8000, P=16 pairs covering channels 0..31.
// Pure memory-bound permuted copy; float4-vectorized, fully coalesced.

#define B_DIM 128
#define C_DIM 64
#define T_DIM 8000
#define T4    (T_DIM / 4)          // 2000 float4 per row
#define P_DIM 16
#define BLOCKS_PER_ROW 8           // 8 * 256 threads = 2048 >= 2000

// --- mask-layout detection -------------------------------------------------
// swap_mask is bool[128][16] in the reference. Depending on harness dtype
// handling it may arrive as 1-byte bools OR widened little-endian int32 0/1.
// Detect: scan the first n bytes; if ANY byte at position i%4 != 0 is
// nonzero, it must be byte-packed bools (stride 1). If all such bytes are
// zero it is int32 (values 0/1 -> upper 3 bytes always 0) -> stride 4.
// For a random 50% bool mask the false-detect probability is 2^-1536.
__global__ void detect_mask_stride_kernel(const unsigned char* __restrict__ m,
                                          int n_bytes, int* __restrict__ flag) {
    __shared__ int any_hi;
    if (threadIdx.x == 0) any_hi = 0;
    __syncthreads();
    int local = 0;
    for (int i = threadIdx.x; i < n_bytes; i += blockDim.x) {
        if ((i & 3) != 0 && m[i] != 0) local = 1;
    }
    if (local) atomicOr(&any_hi, 1);
    __syncthreads();
    if (threadIdx.x == 0) *flag = any_hi ? 1 : 4;   // byte stride per element
}

// --- main permuted copy ----------------------------------------------------
__global__ __launch_bounds__(256) void
ChannelSymmetry_42339787603992_kernel(const float4* __restrict__ X,
                                      const unsigned char* __restrict__ mask,
                                      const int* __restrict__ mask_stride,
                                      float4* __restrict__ Y) {
    // 1D grid: blockIdx.x = row * BLOCKS_PER_ROW + chunk
    const int row   = blockIdx.x >> 3;          // 0 .. B*C-1
    const int chunk = blockIdx.x & (BLOCKS_PER_ROW - 1);
    const int col   = chunk * 256 + threadIdx.x;
    if (col >= T4) return;

    const int b = row >> 6;        // / C_DIM
    const int c = row & 63;        // % C_DIM

    int sc = c;
    if (c < 32) {
        const int p  = c >> 1;
        const int ms = *mask_stride;                    // 1 or 4 (broadcast, L2-hot)
        const unsigned char sw = mask[(b * P_DIM + p) * ms];
        if (sw) sc = c ^ 1;
    }

    const size_t dst = (size_t)row * T4 + col;
    const size_t src = (size_t)((b << 6) | sc) * T4 + col;
    Y[dst] = X[src];
}

extern "C" void kernel_launch(void* const* d_in, const int* in_sizes, int n_in,
                              void* d_out, int out_size, void* d_ws, size_t ws_size,
                              hipStream_t stream) {
    const float4*        X    = (const float4*)d_in[0];
    const unsigned char* mask = (const unsigned char*)d_in[1];
    float4*              Y    = (float4*)d_out;
    int*                 flag = (int*)d_ws;

    // swap_mask element count = B*P = 2048; scanning that many BYTES is safe
    // in both layouts (bool buffer is exactly 2048 B; int32 buffer is 8192 B).
    const int mask_elems = in_sizes[1];
    detect_mask_stride_kernel<<<1, 256, 0, stream>>>(mask, mask_elems, flag);

    const int n_rows = B_DIM * C_DIM;                 // 8192
    const int grid   = n_rows * BLOCKS_PER_ROW;       // 65536 blocks
    ChannelSymmetry_42339787603992_kernel<<<grid, 256, 0, stream>>>(X, mask, flag, Y);
}